// Round 1
// baseline (1334.038 us; speedup 1.0000x reference)
//
#include <hip/hip_runtime.h>
#include <cstdint>
#include <cstddef>

#define NNODES 500000
#define MEM    172
#define RAW    512
#define BATCH  100000

#define KP   192   // padded K for GEMM2 (172 -> 192, zeros)
#define NP1  176   // GEMM1 padded output cols (172 -> 176)

// ws layout (bytes)
#define WR_OFF   0u          // [176][512] bf16 = 180224
#define WIH_OFF  180224u     // [528][192] bf16 = 202752
#define WHH_OFF  382976u     // [528][192] bf16 = 202752
#define BIH_OFF  585728u     // [528] f32
#define BHH_OFF  587840u     // [528] f32  (end 589952)

typedef __attribute__((ext_vector_type(4))) float f32x4;
typedef __attribute__((ext_vector_type(8))) short bf16x8;

__device__ __forceinline__ unsigned short f2bf(float f) {
    unsigned int u = __builtin_bit_cast(unsigned int, f);
    u = (u + 0x7FFFu + ((u >> 16) & 1u)) >> 16;
    return (unsigned short)u;
}
__device__ __forceinline__ float bf2f(unsigned short s) {
    unsigned int u = ((unsigned int)s) << 16;
    return __builtin_bit_cast(float, u);
}

// ---------------- prep: convert/pad weights + biases into ws ----------------
__global__ void prep_kernel(const float* __restrict__ Wr,
                            const float* __restrict__ wih,
                            const float* __restrict__ whh,
                            const float* __restrict__ bih,
                            const float* __restrict__ bhh,
                            unsigned char* __restrict__ ws) {
    unsigned short* wr_b  = (unsigned short*)(ws + WR_OFF);
    unsigned short* wih_p = (unsigned short*)(ws + WIH_OFF);
    unsigned short* whh_p = (unsigned short*)(ws + WHH_OFF);
    float* bih_p = (float*)(ws + BIH_OFF);
    float* bhh_p = (float*)(ws + BHH_OFF);

    int stride = gridDim.x * blockDim.x;
    int g0 = blockIdx.x * blockDim.x + threadIdx.x;

    // W_reduce: [172][512] f32 -> [176][512] bf16 (rows >=172 zero)
    for (int i = g0; i < NP1 * RAW; i += stride) {
        int n = i / RAW, k = i - n * RAW;
        wr_b[i] = f2bf(n < MEM ? Wr[n * RAW + k] : 0.f);
    }
    // w_ih / w_hh: [516][172] -> [528][192] bf16, gate-aligned padding
    for (int i = g0; i < 528 * KP; i += stride) {
        int j = i / KP, k = i - j * KP;
        int g = j / NP1, m = j - g * NP1;
        float vi = 0.f, vh = 0.f;
        if (m < MEM && k < MEM) {
            vi = wih[(g * MEM + m) * MEM + k];
            vh = whh[(g * MEM + m) * MEM + k];
        }
        wih_p[i] = f2bf(vi);
        whh_p[i] = f2bf(vh);
    }
    // biases -> padded [528]
    for (int i = g0; i < 528; i += stride) {
        int g = i / NP1, m = i - g * NP1;
        bih_p[i] = (m < MEM) ? bih[g * MEM + m] : 0.f;
        bhh_p[i] = (m < MEM) ? bhh[g * MEM + m] : 0.f;
    }
}

// ---------------- copy: node_memories -> out (float4) ----------------
__global__ void copy_kernel(const f32x4* __restrict__ src, f32x4* __restrict__ dst, int n4) {
    int stride = gridDim.x * blockDim.x;
    for (int i = blockIdx.x * blockDim.x + threadIdx.x; i < n4; i += stride)
        dst[i] = src[i];
}

// ---------------- fused: GEMM1 + gather + GRU GEMM2 + gates + scatter ----------------
__launch_bounds__(256)
__global__ void fused_kernel(const float* __restrict__ nm,
                             const float* __restrict__ X,
                             const int*   __restrict__ ids,
                             const unsigned char* __restrict__ ws,
                             float* __restrict__ out) {
    __shared__ unsigned short s_msgs[64][KP];
    __shared__ unsigned short s_h[64][KP];
    __shared__ int s_ids[64];

    const unsigned short* wr_b  = (const unsigned short*)(ws + WR_OFF);
    const unsigned short* wih_p = (const unsigned short*)(ws + WIH_OFF);
    const unsigned short* whh_p = (const unsigned short*)(ws + WHH_OFF);
    const float* bih_p = (const float*)(ws + BIH_OFF);
    const float* bhh_p = (const float*)(ws + BHH_OFF);

    const int tid  = threadIdx.x;
    const int lane = tid & 63;
    const int w    = tid >> 6;       // wave 0..3, owns rows w*16..w*16+15
    const int l15  = lane & 15;
    const int lq   = lane >> 4;      // 0..3
    const int row0 = blockIdx.x * 64;

    if (tid < 64) {
        int gr = row0 + tid;
        s_ids[tid] = (gr < BATCH) ? ids[gr] : 0;
    }

    // ---- phase 1: msgs[64][176] = X[64][512] @ Wr^T ----
    const int grA = row0 + w * 16 + l15;   // A-operand row this lane supplies
    f32x4 acc1[11];
#pragma unroll
    for (int t = 0; t < 11; ++t) acc1[t] = f32x4{0.f, 0.f, 0.f, 0.f};

    const f32x4* x4 = (const f32x4*)X;     // 128 f32x4 per row
#pragma unroll 1
    for (int ks = 0; ks < 16; ++ks) {
        const int k0 = ks * 32;
        bf16x8 a;
        if (grA < BATCH) {
            f32x4 f0 = x4[grA * 128 + ks * 8 + lq * 2];
            f32x4 f1 = x4[grA * 128 + ks * 8 + lq * 2 + 1];
#pragma unroll
            for (int e = 0; e < 4; ++e) {
                a[e]     = (short)f2bf(f0[e]);
                a[4 + e] = (short)f2bf(f1[e]);
            }
        } else {
            a = bf16x8{0, 0, 0, 0, 0, 0, 0, 0};
        }
#pragma unroll
        for (int t = 0; t < 11; ++t) {
            bf16x8 b = *(const bf16x8*)&wr_b[(t * 16 + l15) * RAW + k0 + lq * 8];
            acc1[t] = __builtin_amdgcn_mfma_f32_16x16x32_bf16(a, b, acc1[t], 0, 0, 0);
        }
    }
    // store msgs to LDS (bf16), zero pad cols 176..191
#pragma unroll
    for (int t = 0; t < 11; ++t) {
#pragma unroll
        for (int r = 0; r < 4; ++r) {
            int rl = w * 16 + lq * 4 + r;
            s_msgs[rl][t * 16 + l15] = f2bf(acc1[t][r]);
        }
    }
#pragma unroll
    for (int r = 0; r < 4; ++r) {
        int rl = w * 16 + lq * 4 + r;
        s_msgs[rl][176 + l15] = 0;
    }

    // ---- phase 2: gather h rows -> LDS bf16 (padded) ----
    const f32x4* nm4 = (const f32x4*)nm;   // 43 f32x4 per row
    for (int i = tid; i < 64 * 48; i += 256) {
        int rl = i / 48, q = i - rl * 48;
        int gr = row0 + rl;
        f32x4 v = f32x4{0.f, 0.f, 0.f, 0.f};
        if (gr < BATCH && q < 43) {
            int id = ids[gr];
            v = nm4[(long)id * 43 + q];
        }
        unsigned short* p = &s_h[rl][q * 4];
        p[0] = f2bf(v[0]); p[1] = f2bf(v[1]); p[2] = f2bf(v[2]); p[3] = f2bf(v[3]);
    }

    __syncthreads();

    // ---- phase 3: GEMM2 — gi/gh over padded [528] cols ----
    // tiles 0..21  : r,z sections -> accumulate BOTH msgs*Wih and h*Whh (+b_ih+b_hh)
    // tiles 22..32 : n section    -> separate i_n (msgs*Wih + b_ih) and h_n (h*Whh + b_hh)
    f32x4 accRZ[22], accNi[11], accNh[11];
#pragma unroll
    for (int t = 0; t < 22; ++t) {
        float bs = bih_p[t * 16 + l15] + bhh_p[t * 16 + l15];
        accRZ[t] = f32x4{bs, bs, bs, bs};
    }
#pragma unroll
    for (int t = 0; t < 11; ++t) {
        float bi = bih_p[352 + t * 16 + l15];
        float bh = bhh_p[352 + t * 16 + l15];
        accNi[t] = f32x4{bi, bi, bi, bi};
        accNh[t] = f32x4{bh, bh, bh, bh};
    }

#pragma unroll 1
    for (int ks = 0; ks < 6; ++ks) {
        const int k0 = ks * 32;
        bf16x8 am = *(const bf16x8*)&s_msgs[w * 16 + l15][k0 + lq * 8];
        bf16x8 ah = *(const bf16x8*)&s_h[w * 16 + l15][k0 + lq * 8];
#pragma unroll
        for (int t = 0; t < 22; ++t) {
            bf16x8 bi_ = *(const bf16x8*)&wih_p[(t * 16 + l15) * KP + k0 + lq * 8];
            accRZ[t] = __builtin_amdgcn_mfma_f32_16x16x32_bf16(am, bi_, accRZ[t], 0, 0, 0);
            bf16x8 bh_ = *(const bf16x8*)&whh_p[(t * 16 + l15) * KP + k0 + lq * 8];
            accRZ[t] = __builtin_amdgcn_mfma_f32_16x16x32_bf16(ah, bh_, accRZ[t], 0, 0, 0);
        }
#pragma unroll
        for (int t = 0; t < 11; ++t) {
            bf16x8 bi_ = *(const bf16x8*)&wih_p[((22 + t) * 16 + l15) * KP + k0 + lq * 8];
            accNi[t] = __builtin_amdgcn_mfma_f32_16x16x32_bf16(am, bi_, accNi[t], 0, 0, 0);
            bf16x8 bh_ = *(const bf16x8*)&whh_p[((22 + t) * 16 + l15) * KP + k0 + lq * 8];
            accNh[t] = __builtin_amdgcn_mfma_f32_16x16x32_bf16(ah, bh_, accNh[t], 0, 0, 0);
        }
    }

    // ---- phase 4: gates + scatter ----
#pragma unroll
    for (int t = 0; t < 11; ++t) {
        int m = t * 16 + l15;
        if (m < MEM) {
#pragma unroll
            for (int r = 0; r < 4; ++r) {
                int rl = w * 16 + lq * 4 + r;
                int gr = row0 + rl;
                if (gr < BATCH) {
                    float rg = 1.f / (1.f + __expf(-accRZ[t][r]));
                    float zg = 1.f / (1.f + __expf(-accRZ[11 + t][r]));
                    float ng = tanhf(accNi[t][r] + rg * accNh[t][r]);
                    float h  = bf2f(s_h[rl][m]);
                    float o  = (1.f - zg) * ng + zg * h;
                    out[(long)s_ids[rl] * MEM + m] = o;
                }
            }
        }
    }
}

extern "C" void kernel_launch(void* const* d_in, const int* in_sizes, int n_in,
                              void* d_out, int out_size, void* d_ws, size_t ws_size,
                              hipStream_t stream) {
    const float* nm  = (const float*)d_in[0];   // [500000*172]
    const float* X   = (const float*)d_in[1];   // [100000*512]
    const float* Wr  = (const float*)d_in[2];   // [172*512]
    const float* wih = (const float*)d_in[3];   // [516*172]
    const float* whh = (const float*)d_in[4];   // [516*172]
    const float* bih = (const float*)d_in[5];   // [516]
    const float* bhh = (const float*)d_in[6];   // [516]
    const int*   ids = (const int*)d_in[7];     // [100000]
    float* out = (float*)d_out;
    unsigned char* ws = (unsigned char*)d_ws;

    // 1) weights -> bf16 padded in ws
    prep_kernel<<<400, 256, 0, stream>>>(Wr, wih, whh, bih, bhh, ws);

    // 2) full copy node_memories -> out
    const int n4 = (NNODES * MEM) / 4;  // 21.5M float4
    copy_kernel<<<4096, 256, 0, stream>>>((const f32x4*)nm, (f32x4*)out, n4);

    // 3) fused GEMM1 + gather + GRU + scatter (after copy in stream order)
    const int nblocks = (BATCH + 63) / 64;  // 1563
    fused_kernel<<<nblocks, 256, 0, stream>>>(nm, X, ids, ws, out);
}